// Round 3
// baseline (863.120 us; speedup 1.0000x reference)
//
#include <hip/hip_runtime.h>
#include <hip/hip_bf16.h>

#define NN 50000      // nodes
#define NE 800000     // edges
#define NR 20         // relations
#define NB 8          // bases
#define D  128        // hidden dim
#define DO 64         // output dim
#define GSZ 196       // dst nodes per group
#define NG 256        // groups; NG*GSZ = 50176 >= NN

typedef __attribute__((ext_vector_type(8))) short short8;
typedef __attribute__((ext_vector_type(4))) float f32x4;

__device__ inline unsigned short f2bf(float f) {
    __hip_bfloat16 h = __float2bfloat16(f);
    return *reinterpret_cast<unsigned short*>(&h);
}

// ---------------------------------------------------------------------------
// ws layout (bytes):
//   [0        ..  4,000,000) cnt    NN*NR int      -- zeroed each call
//   [4,000,000..  4,020,480) ghist  NG*NR int      -- zeroed each call
//   [4,020,480..  4,040,960) gcur   NG*NR int      -- written by k_scan
//   [4,040,960..  4,061,444) goff   NG*NR+1 int
//   [4,061,504..  4,071,744) W0     NR*D f32
//   [4,071,744..  4,727,104) W1b    NR*16384 bf16  (B-fragment order)
//   [4,727,104.. 17,527,104) h1b    NN*D bf16
//   [17,527,104..20,727,104) epack  NE int  ((dl<<16)|src, sorted by (g,rel))
// ---------------------------------------------------------------------------

// W0[r,o] = sum_b wcomp0[r,b]*basis0[b,0,o]  (f32)
// W1b in MFMA B-fragment layout (r2-verified):
//   task = ((rel*4 + kc)*8 + cb)*64 + lane ; elem e:
//   value = W1[rel][kc*32 + (lane>>4)*8 + e][cb*16 + (lane&15)]
__global__ __launch_bounds__(256) void k_weights(
        const float* __restrict__ basis0, const float* __restrict__ wcomp0,
        const float* __restrict__ basis1, const float* __restrict__ wcomp1,
        float* __restrict__ W0, unsigned short* __restrict__ W1b) {
    int idx = blockIdx.x * 256 + threadIdx.x;   // 0..40959
    if (idx < NR * D) {
        int r = idx / D, o = idx % D;
        float a = 0.f;
        #pragma unroll
        for (int b = 0; b < NB; b++) a += wcomp0[r * NB + b] * basis0[b * D + o];
        W0[idx] = a;
    }
    if (idx < NR * 4 * 8 * 64) {
        int lane = idx & 63;
        int cb   = (idx >> 6) & 7;
        int kc   = (idx >> 9) & 3;
        int rel  = idx >> 11;
        float wc[NB];
        #pragma unroll
        for (int b = 0; b < NB; b++) wc[b] = wcomp1[rel * NB + b];
        int o  = cb * 16 + (lane & 15);
        int i0 = kc * 32 + (lane >> 4) * 8;
        short8 v;
        #pragma unroll
        for (int e = 0; e < 8; e++) {
            int i = i0 + e;
            float a = 0.f;
            #pragma unroll
            for (int b = 0; b < NB; b++) a += wc[b] * basis1[(b * D + i) * D + o];
            v[e] = (short)f2bf(a);
        }
        *((short8*)W1b + idx) = v;
    }
}

// Per-(dst,rel) histogram (layer-0 counts) + per-(group,rel) bucket histogram.
__global__ __launch_bounds__(1024) void k_hist(
        const int* __restrict__ dst, const int* __restrict__ et,
        int* __restrict__ cnt, int* __restrict__ ghist) {
    int i = blockIdx.x * 1024 + threadIdx.x;
    if (i < NE) {
        int d = dst[i], e = et[i];
        atomicAdd(&cnt[d * NR + e], 1);
        int g = d / GSZ;
        atomicAdd(&ghist[g * NR + e], 1);
    }
}

// Exclusive scan over NG*NR = 5120 bucket counts (single block).
__global__ __launch_bounds__(1024) void k_scan(const int* __restrict__ ghist,
                                               int* __restrict__ goff,
                                               int* __restrict__ gcur) {
    __shared__ int wsum[16];
    int t = threadIdx.x, lane = t & 63, wav = t >> 6;
    int v[5]; int s = 0;
    #pragma unroll
    for (int j = 0; j < 5; j++) {
        int idx = t * 5 + j;
        v[j] = (idx < NG * NR) ? ghist[idx] : 0;
        s += v[j];
    }
    int inc = s;
    for (int dd = 1; dd < 64; dd <<= 1) {
        int u = __shfl_up(inc, dd);
        if (lane >= dd) inc += u;
    }
    if (lane == 63) wsum[wav] = inc;
    __syncthreads();
    if (t == 0) { int a = 0; for (int i = 0; i < 16; i++) { int x = wsum[i]; wsum[i] = a; a += x; } }
    __syncthreads();
    int base = wsum[wav] + inc - s;
    #pragma unroll
    for (int j = 0; j < 5; j++) {
        int idx = t * 5 + j;
        if (idx < NG * NR) { goff[idx] = base; gcur[idx] = base; }
        base += v[j];
    }
    if (t == 1023) goff[NG * NR] = base;
}

// Counting-sort scatter into (group,rel) buckets; payload packs (dl<<16)|src.
__global__ __launch_bounds__(1024) void k_scatter(
        const int* __restrict__ src, const int* __restrict__ dst,
        const int* __restrict__ et, int* __restrict__ gcur,
        int* __restrict__ epack) {
    int i = blockIdx.x * 1024 + threadIdx.x;
    if (i < NE) {
        int d = dst[i], e = et[i];
        int g = d / GSZ, dl = d - g * GSZ;
        int pos = atomicAdd(&gcur[g * NR + e], 1);
        epack[pos] = (dl << 16) | src[i];
    }
}

// h1b[n] = bf16(relu(bias0 + sum_r cnt[n,r]*W0[r]))   (layer 0, h = ones)
__global__ __launch_bounds__(128) void k_h1(const int* __restrict__ cnt,
                                            const float* __restrict__ W0,
                                            const float* __restrict__ bias0,
                                            unsigned short* __restrict__ h1b) {
    int n = blockIdx.x, t = threadIdx.x;
    __shared__ float cs[NR];
    if (t < NR) cs[t] = (float)cnt[n * NR + t];
    __syncthreads();
    float acc = bias0[t];
    #pragma unroll
    for (int r = 0; r < NR; r++) acc += cs[r] * W0[r * D + t];
    h1b[n * D + t] = f2bf(fmaxf(acc, 0.f));
}

// Mega kernel: one block per dst-group. LDS accumulator agg[GSZ][128] (f32,
// col XOR-swizzled by dl&3). Per relation: 64-edge MFMA tiles, 4 quads of 4
// waves; A gathered direct from h1b (L2/L3-resident), B from W1b fragments.
// Fused epilogue: bias1+relu then x@lin_w+lin_b -> out.
__global__ __launch_bounds__(1024, 1) void k_mega(
        const int* __restrict__ epack, const int* __restrict__ goff,
        const unsigned short* __restrict__ h1b,
        const unsigned short* __restrict__ W1b,
        const float* __restrict__ bias1, const float* __restrict__ lin_w,
        const float* __restrict__ lin_b, float* __restrict__ out) {
    __shared__ float agg[GSZ * D];       // 100,352 B
    __shared__ int epk[4][64];
    int t = threadIdx.x, g = blockIdx.x;
    int quad = t >> 8, lane = t & 63, wq = (t >> 6) & 3;
    int row = lane & 15, gg = lane >> 4;

    for (int i = t; i < GSZ * D; i += 1024) agg[i] = 0.f;
    __syncthreads();

    for (int r = 0; r < NR; r++) {
        int start = goff[g * NR + r], end = goff[g * NR + r + 1];
        int ntile = (end - start + 63) >> 6;
        int nstep = (ntile + 3) >> 2;
        for (int sstep = 0; sstep < nstep; sstep++) {
            int ti = sstep * 4 + quad;
            int base = start + ti * 64;
            int m = min(64, end - base);
            if (wq == 0) {
                int vv = 0;
                if (ti < ntile && lane < m) vv = epack[base + lane];
                epk[quad][lane] = vv;
            }
            __syncthreads();
            if (ti < ntile) {
                int src = epk[quad][wq * 16 + row] & 0xFFFF;
                const short8* Ap = (const short8*)(h1b + src * D) + gg;
                short8 a0 = Ap[0], a1 = Ap[4], a2 = Ap[8], a3 = Ap[12];
                const short8* Wv = (const short8*)W1b + r * 2048 + lane;
                f32x4 acc[8];
                #pragma unroll
                for (int cb = 0; cb < 8; cb++) acc[cb] = (f32x4){0.f, 0.f, 0.f, 0.f};
                #pragma unroll
                for (int cb = 0; cb < 8; cb++)
                    acc[cb] = __builtin_amdgcn_mfma_f32_16x16x32_bf16(a0, Wv[(0  + cb) * 64], acc[cb], 0, 0, 0);
                #pragma unroll
                for (int cb = 0; cb < 8; cb++)
                    acc[cb] = __builtin_amdgcn_mfma_f32_16x16x32_bf16(a1, Wv[(8  + cb) * 64], acc[cb], 0, 0, 0);
                #pragma unroll
                for (int cb = 0; cb < 8; cb++)
                    acc[cb] = __builtin_amdgcn_mfma_f32_16x16x32_bf16(a2, Wv[(16 + cb) * 64], acc[cb], 0, 0, 0);
                #pragma unroll
                for (int cb = 0; cb < 8; cb++)
                    acc[cb] = __builtin_amdgcn_mfma_f32_16x16x32_bf16(a3, Wv[(24 + cb) * 64], acc[cb], 0, 0, 0);
                // C/D layout: col = cb*16 + (lane&15), er = wq*16 + (lane>>4)*4 + reg
                int dls[4];
                #pragma unroll
                for (int reg = 0; reg < 4; reg++) {
                    int er = wq * 16 + gg * 4 + reg;
                    dls[reg] = (er < m) ? (epk[quad][er] >> 16) : -1;
                }
                #pragma unroll
                for (int cb = 0; cb < 8; cb++) {
                    int col = cb * 16 + row;
                    #pragma unroll
                    for (int reg = 0; reg < 4; reg++) {
                        if (dls[reg] >= 0) {
                            atomicAdd(&agg[dls[reg] * D + (col ^ ((dls[reg] & 3) << 4))],
                                      acc[cb][reg]);
                        }
                    }
                }
            }
            __syncthreads();
        }
    }

    // bias + relu in place
    for (int i = t; i < GSZ * D; i += 1024) {
        int dl = i >> 7, colp = i & 127, col = colp ^ ((dl & 3) << 4);
        agg[i] = fmaxf(agg[i] + bias1[col], 0.f);
    }
    __syncthreads();

    // linear 128 -> 64 : wave handles one dl at a time, lane = output col
    int gsz = min(GSZ, NN - g * GSZ);
    int wav = t >> 6;
    for (int dl = wav; dl < gsz; dl += 16) {
        int sw = (dl & 3) << 4;
        float acc = lin_b[lane];
        #pragma unroll 8
        for (int k = 0; k < D; k++)
            acc += agg[dl * D + (k ^ sw)] * lin_w[k * DO + lane];
        out[(g * GSZ + dl) * DO + lane] = acc;
    }
}

extern "C" void kernel_launch(void* const* d_in, const int* in_sizes, int n_in,
                              void* d_out, int out_size, void* d_ws, size_t ws_size,
                              hipStream_t stream) {
    const int*   src    = (const int*)d_in[0];
    const int*   dst    = (const int*)d_in[1];
    const int*   et     = (const int*)d_in[2];
    const float* basis0 = (const float*)d_in[4];
    const float* wcomp0 = (const float*)d_in[5];
    const float* bias0  = (const float*)d_in[6];
    const float* basis1 = (const float*)d_in[7];
    const float* wcomp1 = (const float*)d_in[8];
    const float* bias1  = (const float*)d_in[9];
    const float* lin_w  = (const float*)d_in[10];
    const float* lin_b  = (const float*)d_in[11];
    float* out = (float*)d_out;

    char* ws = (char*)d_ws;
    int*            cnt   = (int*)           (ws + 0);
    int*            ghist = (int*)           (ws + 4000000);
    int*            gcur  = (int*)           (ws + 4020480);
    int*            goff  = (int*)           (ws + 4040960);
    float*          W0    = (float*)         (ws + 4061504);
    unsigned short* W1b   = (unsigned short*)(ws + 4071744);
    unsigned short* h1b   = (unsigned short*)(ws + 4727104);
    int*            epack = (int*)           (ws + 17527104);

    // zero cnt + ghist (gcur is written by k_scan)
    hipMemsetAsync(ws, 0, 4020480, stream);

    k_weights<<<160, 256, 0, stream>>>(basis0, wcomp0, basis1, wcomp1, W0, W1b);
    k_hist<<<(NE + 1023) / 1024, 1024, 0, stream>>>(dst, et, cnt, ghist);
    k_scan<<<1, 1024, 0, stream>>>(ghist, goff, gcur);
    k_scatter<<<(NE + 1023) / 1024, 1024, 0, stream>>>(src, dst, et, gcur, epack);
    k_h1<<<NN, 128, 0, stream>>>(cnt, W0, bias0, h1b);
    k_mega<<<NG, 1024, 0, stream>>>(epack, goff, h1b, W1b, bias1, lin_w, lin_b, out);
}

// Round 4
// 799.420 us; speedup vs baseline: 1.0797x; 1.0797x over previous
//
#include <hip/hip_runtime.h>
#include <hip/hip_bf16.h>

#define NN 50000      // nodes
#define NE 800000     // edges
#define NR 20         // relations
#define NB 8          // bases
#define D  128        // hidden dim
#define DO 64         // output dim
#define GSZ 98        // dst nodes per group
#define NG 512        // groups; covers 50176 >= NN (last blocks partially/fully empty)
#define EPK_CAP 3072  // staged+padded edge slots per group (mean ~2560 incl. pad, 5-sigma safe)

typedef __attribute__((ext_vector_type(8))) short short8;
typedef __attribute__((ext_vector_type(4))) float f32x4;

__device__ inline unsigned short f2bf(float f) {
    __hip_bfloat16 h = __float2bfloat16(f);
    return *reinterpret_cast<unsigned short*>(&h);
}

// ---------------------------------------------------------------------------
// ws layout (bytes):
//   [0        ..  4,000,000) cnt    NN*NR int      -- zeroed each call
//   [4,000,000..  4,040,960) ghist  NG*NR int      -- zeroed each call
//   [4,040,960..  4,081,920) gcur   NG*NR int      -- written by k_scan
//   [4,081,920..  4,122,884) goff   NG*NR+1 int
//   [4,122,944..  4,133,184) W0     NR*D f32
//   [4,133,184..  4,788,544) W1b    NR*16384 bf16  (B-fragment order)
//   [4,788,544.. 17,588,544) h1b    NN*D bf16
//   [17,588,544..20,788,544) epack  NE int  ((dl<<16)|src, sorted by (g,rel))
//   (pad-slot gathers may read up to ws+21.6MB -- inside proven ws_size >= 59.7MB)
// ---------------------------------------------------------------------------

// W0[r,o] = sum_b wcomp0[r,b]*basis0[b,0,o]  (f32)
// W1b in MFMA B-fragment layout (r2/r3-verified):
//   task = ((rel*4 + kc)*8 + cb)*64 + lane ; elem e:
//   value = W1[rel][kc*32 + (lane>>4)*8 + e][cb*16 + (lane&15)]
__global__ __launch_bounds__(256) void k_weights(
        const float* __restrict__ basis0, const float* __restrict__ wcomp0,
        const float* __restrict__ basis1, const float* __restrict__ wcomp1,
        float* __restrict__ W0, unsigned short* __restrict__ W1b) {
    int idx = blockIdx.x * 256 + threadIdx.x;   // 0..40959
    if (idx < NR * D) {
        int r = idx / D, o = idx % D;
        float a = 0.f;
        #pragma unroll
        for (int b = 0; b < NB; b++) a += wcomp0[r * NB + b] * basis0[b * D + o];
        W0[idx] = a;
    }
    if (idx < NR * 4 * 8 * 64) {
        int lane = idx & 63;
        int cb   = (idx >> 6) & 7;
        int kc   = (idx >> 9) & 3;
        int rel  = idx >> 11;
        float wc[NB];
        #pragma unroll
        for (int b = 0; b < NB; b++) wc[b] = wcomp1[rel * NB + b];
        int o  = cb * 16 + (lane & 15);
        int i0 = kc * 32 + (lane >> 4) * 8;
        short8 v;
        #pragma unroll
        for (int e = 0; e < 8; e++) {
            int i = i0 + e;
            float a = 0.f;
            #pragma unroll
            for (int b = 0; b < NB; b++) a += wc[b] * basis1[(b * D + i) * D + o];
            v[e] = (short)f2bf(a);
        }
        *((short8*)W1b + idx) = v;
    }
}

// Per-(dst,rel) histogram (layer-0 counts) + per-(group,rel) bucket histogram.
__global__ __launch_bounds__(1024) void k_hist(
        const int* __restrict__ dst, const int* __restrict__ et,
        int* __restrict__ cnt, int* __restrict__ ghist) {
    int i = blockIdx.x * 1024 + threadIdx.x;
    if (i < NE) {
        int d = dst[i], e = et[i];
        atomicAdd(&cnt[d * NR + e], 1);
        int g = d / GSZ;
        atomicAdd(&ghist[g * NR + e], 1);
    }
}

// Exclusive scan over NG*NR = 10240 bucket counts (single block, 10/thread).
__global__ __launch_bounds__(1024) void k_scan(const int* __restrict__ ghist,
                                               int* __restrict__ goff,
                                               int* __restrict__ gcur) {
    __shared__ int wsum[16];
    int t = threadIdx.x, lane = t & 63, wav = t >> 6;
    int v[10]; int s = 0;
    #pragma unroll
    for (int j = 0; j < 10; j++) {
        int idx = t * 10 + j;
        v[j] = (idx < NG * NR) ? ghist[idx] : 0;
        s += v[j];
    }
    int inc = s;
    for (int dd = 1; dd < 64; dd <<= 1) {
        int u = __shfl_up(inc, dd);
        if (lane >= dd) inc += u;
    }
    if (lane == 63) wsum[wav] = inc;
    __syncthreads();
    if (t == 0) { int a = 0; for (int i = 0; i < 16; i++) { int x = wsum[i]; wsum[i] = a; a += x; } }
    __syncthreads();
    int base = wsum[wav] + inc - s;
    #pragma unroll
    for (int j = 0; j < 10; j++) {
        int idx = t * 10 + j;
        if (idx < NG * NR) { goff[idx] = base; gcur[idx] = base; }
        base += v[j];
    }
    if (t == 1023) goff[NG * NR] = base;
}

// Counting-sort scatter into (group,rel) buckets; payload packs (dl<<16)|src.
__global__ __launch_bounds__(1024) void k_scatter(
        const int* __restrict__ src, const int* __restrict__ dst,
        const int* __restrict__ et, int* __restrict__ gcur,
        int* __restrict__ epack) {
    int i = blockIdx.x * 1024 + threadIdx.x;
    if (i < NE) {
        int d = dst[i], e = et[i];
        int g = d / GSZ, dl = d - g * GSZ;
        int pos = atomicAdd(&gcur[g * NR + e], 1);
        epack[pos] = (dl << 16) | src[i];
    }
}

// h1b[n] = bf16(relu(bias0 + sum_r cnt[n,r]*W0[r]))   (layer 0, h = ones)
__global__ __launch_bounds__(128) void k_h1(const int* __restrict__ cnt,
                                            const float* __restrict__ W0,
                                            const float* __restrict__ bias0,
                                            unsigned short* __restrict__ h1b) {
    int n = blockIdx.x, t = threadIdx.x;
    __shared__ float cs[NR];
    if (t < NR) cs[t] = (float)cnt[n * NR + t];
    __syncthreads();
    float acc = bias0[t];
    #pragma unroll
    for (int r = 0; r < NR; r++) acc += cs[r] * W0[r * D + t];
    h1b[n * D + t] = f2bf(fmaxf(acc, 0.f));
}

// Mega kernel v2: one block per dst-group (512 thr, 2 blocks/CU).
//  - Stage group's sorted edge list into LDS once, padded to 64-edge tiles
//    (pad = 0xFFFF0000: src=0 (cached row), dl=-1 (discarded)).
//  - Barrier-free main loop: 2 quads (4 waves each) free-run over tiles,
//    2-deep prefetch of A-rows; accumulate via LDS atomics into agg.
//  - Fused epilogue: bias1+relu then @lin_w+lin_b -> out.
__global__ __launch_bounds__(512, 4) void k_mega(
        const int* __restrict__ epack, const int* __restrict__ goff,
        const unsigned short* __restrict__ h1b,
        const unsigned short* __restrict__ W1b,
        const float* __restrict__ bias1, const float* __restrict__ lin_w,
        const float* __restrict__ lin_b, float* __restrict__ out) {
    __shared__ float agg[GSZ * D];       // 50,176 B
    __shared__ int epk[EPK_CAP];         // 12,288 B
    __shared__ int soff[NR + 1];
    __shared__ int tbase[NR + 1];        // padded slot offset per rel
    __shared__ int tpre[NR + 1];         // tile-count prefix per rel
    int t = threadIdx.x, g = blockIdx.x;
    int wave = t >> 6, lane = t & 63;
    int quad = wave >> 2, wq = wave & 3;
    int row = lane & 15, gg = lane >> 4;

    for (int i = t; i < GSZ * D; i += 512) agg[i] = 0.f;
    if (t <= NR) soff[t] = goff[g * NR + t];
    __syncthreads();

    if (t == 0) {
        int sb = 0, tb = 0;
        for (int r = 0; r < NR; r++) {
            tbase[r] = sb; tpre[r] = tb;
            int c = soff[r + 1] - soff[r];
            int nt = (c + 63) >> 6;
            sb += nt * 64; tb += nt;
        }
        tbase[NR] = sb; tpre[NR] = tb;
    }
    __syncthreads();

    int S = tbase[NR];
    for (int i = t; i < S; i += 512) {
        int r = 0;
        while (tbase[r + 1] <= i) r++;
        int j = i - tbase[r];
        int c = soff[r + 1] - soff[r];
        epk[i] = (j < c) ? epack[soff[r] + j] : (int)0xFFFF0000;
    }
    __syncthreads();

    int T = tpre[NR];

    // ---- barrier-free main loop, 2-deep prefetch ----
    int k = quad;
    short8 A0 = {0,0,0,0,0,0,0,0}, A1 = A0, A2 = A0, A3 = A0;
    int slotA = 0, relA = 0;
    if (k < T) {
        int r = 0; while (tpre[r + 1] <= k) r++;
        relA = r; slotA = tbase[r] + (k - tpre[r]) * 64;
        int pk = epk[slotA + wq * 16 + row];
        const short8* Ap = (const short8*)(h1b + (pk & 0xFFFF) * D);
        A0 = Ap[gg]; A1 = Ap[4 + gg]; A2 = Ap[8 + gg]; A3 = Ap[12 + gg];
    }
    while (k < T) {
        int kn = k + 2;
        short8 N0 = A0, N1 = A1, N2 = A2, N3 = A3;
        int slotN = slotA, relN = relA;
        if (kn < T) {
            int r = 0; while (tpre[r + 1] <= kn) r++;
            relN = r; slotN = tbase[r] + (kn - tpre[r]) * 64;
            int pk = epk[slotN + wq * 16 + row];
            const short8* Ap = (const short8*)(h1b + (pk & 0xFFFF) * D);
            N0 = Ap[gg]; N1 = Ap[4 + gg]; N2 = Ap[8 + gg]; N3 = Ap[12 + gg];
        }

        f32x4 acc[8];
        #pragma unroll
        for (int cb = 0; cb < 8; cb++) acc[cb] = (f32x4){0.f, 0.f, 0.f, 0.f};
        const short8* Wv = (const short8*)W1b + relA * 2048 + lane;
        #pragma unroll
        for (int cb = 0; cb < 8; cb++)
            acc[cb] = __builtin_amdgcn_mfma_f32_16x16x32_bf16(A0, Wv[(0  + cb) * 64], acc[cb], 0, 0, 0);
        #pragma unroll
        for (int cb = 0; cb < 8; cb++)
            acc[cb] = __builtin_amdgcn_mfma_f32_16x16x32_bf16(A1, Wv[(8  + cb) * 64], acc[cb], 0, 0, 0);
        #pragma unroll
        for (int cb = 0; cb < 8; cb++)
            acc[cb] = __builtin_amdgcn_mfma_f32_16x16x32_bf16(A2, Wv[(16 + cb) * 64], acc[cb], 0, 0, 0);
        #pragma unroll
        for (int cb = 0; cb < 8; cb++)
            acc[cb] = __builtin_amdgcn_mfma_f32_16x16x32_bf16(A3, Wv[(24 + cb) * 64], acc[cb], 0, 0, 0);

        // C/D: col = cb*16 + (lane&15), er = wq*16 + (lane>>4)*4 + reg
        int dls[4];
        #pragma unroll
        for (int reg = 0; reg < 4; reg++)
            dls[reg] = epk[slotA + wq * 16 + gg * 4 + reg] >> 16;
        #pragma unroll
        for (int cb = 0; cb < 8; cb++) {
            int col = cb * 16 + row;
            #pragma unroll
            for (int reg = 0; reg < 4; reg++) {
                if (dls[reg] >= 0) {
                    atomicAdd(&agg[dls[reg] * D + (col ^ ((dls[reg] & 3) << 4))],
                              acc[cb][reg]);
                }
            }
        }

        A0 = N0; A1 = N1; A2 = N2; A3 = N3;
        slotA = slotN; relA = relN; k = kn;
    }
    __syncthreads();

    // bias + relu in place
    for (int i = t; i < GSZ * D; i += 512) {
        int dl = i >> 7, colp = i & 127, col = colp ^ ((dl & 3) << 4);
        agg[i] = fmaxf(agg[i] + bias1[col], 0.f);
    }
    __syncthreads();

    // linear 128 -> 64 : wave handles one dl at a time, lane = output col
    int gsz = min(GSZ, NN - g * GSZ);
    for (int dl = wave; dl < gsz; dl += 8) {
        int sw = (dl & 3) << 4;
        float acc = lin_b[lane];
        #pragma unroll 8
        for (int kk = 0; kk < D; kk++)
            acc += agg[dl * D + (kk ^ sw)] * lin_w[kk * DO + lane];
        out[(g * GSZ + dl) * DO + lane] = acc;
    }
}

extern "C" void kernel_launch(void* const* d_in, const int* in_sizes, int n_in,
                              void* d_out, int out_size, void* d_ws, size_t ws_size,
                              hipStream_t stream) {
    const int*   src    = (const int*)d_in[0];
    const int*   dst    = (const int*)d_in[1];
    const int*   et     = (const int*)d_in[2];
    const float* basis0 = (const float*)d_in[4];
    const float* wcomp0 = (const float*)d_in[5];
    const float* bias0  = (const float*)d_in[6];
    const float* basis1 = (const float*)d_in[7];
    const float* wcomp1 = (const float*)d_in[8];
    const float* bias1  = (const float*)d_in[9];
    const float* lin_w  = (const float*)d_in[10];
    const float* lin_b  = (const float*)d_in[11];
    float* out = (float*)d_out;

    char* ws = (char*)d_ws;
    int*            cnt   = (int*)           (ws + 0);
    int*            ghist = (int*)           (ws + 4000000);
    int*            gcur  = (int*)           (ws + 4040960);
    int*            goff  = (int*)           (ws + 4081920);
    float*          W0    = (float*)         (ws + 4122944);
    unsigned short* W1b   = (unsigned short*)(ws + 4133184);
    unsigned short* h1b   = (unsigned short*)(ws + 4788544);
    int*            epack = (int*)           (ws + 17588544);

    // zero cnt + ghist
    hipMemsetAsync(ws, 0, 4040960, stream);

    k_weights<<<160, 256, 0, stream>>>(basis0, wcomp0, basis1, wcomp1, W0, W1b);
    k_hist<<<(NE + 1023) / 1024, 1024, 0, stream>>>(dst, et, cnt, ghist);
    k_scan<<<1, 1024, 0, stream>>>(ghist, goff, gcur);
    k_scatter<<<(NE + 1023) / 1024, 1024, 0, stream>>>(src, dst, et, gcur, epack);
    k_h1<<<NN, 128, 0, stream>>>(cnt, W0, bias0, h1b);
    k_mega<<<NG, 512, 0, stream>>>(epack, goff, h1b, W1b, bias1, lin_w, lin_b, out);
}

// Round 5
// 293.603 us; speedup vs baseline: 2.9398x; 2.7228x over previous
//
#include <hip/hip_runtime.h>
#include <hip/hip_bf16.h>

#define NN 50000      // nodes
#define NE 800000     // edges
#define NR 20         // relations
#define NB 8          // bases
#define D  128        // hidden dim
#define DO 64         // output dim
#define NT 782        // ceil(NN/64) dst tiles
#define NBKT (NT*1280) // (tile, rel, dl) buckets = 1,000,960
#define NSB 978       // ceil(NBKT/1024)

typedef __attribute__((ext_vector_type(8))) short short8;
typedef __attribute__((ext_vector_type(4))) float f32x4;

__device__ inline unsigned short f2bf(float f) {
    __hip_bfloat16 h = __float2bfloat16(f);
    return *reinterpret_cast<unsigned short*>(&h);
}
__device__ inline float bf2f(unsigned short u) {
    unsigned x = ((unsigned)u) << 16;
    float f;
    __builtin_memcpy(&f, &x, 4);
    return f;
}

// ---------------------------------------------------------------------------
// ws layout (bytes):
//   [0        ..  4,003,840) cnt2  NBKT int   -- zeroed each call; (tile,r,dl) hist
//   [4,003,840..  4,007,752) bsum  NSB int    -- scan block sums
//   [4,007,808..  8,011,652) boff2 NBKT+1 int -- bucket offsets
//   [8,011,712.. 12,015,552) gcur2 NBKT int   -- scatter cursors
//   [12,015,616..12,025,856) W0    NR*D f32
//   [12,025,856..12,681,216) W1b   NR*16384 bf16 (B-fragment order)
//   [12,681,216..25,481,216) h1b   NN*D bf16
//   [25,481,216..28,681,216) epack NE int (src ids, sorted by (tile,r,dl))
// ---------------------------------------------------------------------------

// W0[r,o] = sum_b wcomp0[r,b]*basis0[b,0,o]  (f32)
// W1b in MFMA B-fragment layout (r2/r3-verified):
//   task = ((rel*4 + kc)*8 + cb)*64 + lane ; elem e:
//   value = W1[rel][kc*32 + (lane>>4)*8 + e][cb*16 + (lane&15)]
__global__ __launch_bounds__(256) void k_weights(
        const float* __restrict__ basis0, const float* __restrict__ wcomp0,
        const float* __restrict__ basis1, const float* __restrict__ wcomp1,
        float* __restrict__ W0, unsigned short* __restrict__ W1b) {
    int idx = blockIdx.x * 256 + threadIdx.x;   // 0..40959
    if (idx < NR * D) {
        int r = idx / D, o = idx % D;
        float a = 0.f;
        #pragma unroll
        for (int b = 0; b < NB; b++) a += wcomp0[r * NB + b] * basis0[b * D + o];
        W0[idx] = a;
    }
    if (idx < NR * 4 * 8 * 64) {
        int lane = idx & 63;
        int cb   = (idx >> 6) & 7;
        int kc   = (idx >> 9) & 3;
        int rel  = idx >> 11;
        float wc[NB];
        #pragma unroll
        for (int b = 0; b < NB; b++) wc[b] = wcomp1[rel * NB + b];
        int o  = cb * 16 + (lane & 15);
        int i0 = kc * 32 + (lane >> 4) * 8;
        short8 v;
        #pragma unroll
        for (int e = 0; e < 8; e++) {
            int i = i0 + e;
            float a = 0.f;
            #pragma unroll
            for (int b = 0; b < NB; b++) a += wc[b] * basis1[(b * D + i) * D + o];
            v[e] = (short)f2bf(a);
        }
        *((short8*)W1b + idx) = v;
    }
}

// Histogram over (tile, rel, dl) buckets. Doubles as layer-0 (dst,rel) counts.
__global__ __launch_bounds__(1024) void k_hist(
        const int* __restrict__ dst, const int* __restrict__ et,
        int* __restrict__ cnt2) {
    int i = blockIdx.x * 1024 + threadIdx.x;
    if (i < NE) {
        int d = dst[i];
        int key = (d >> 6) * 1280 + et[i] * 64 + (d & 63);
        atomicAdd(&cnt2[key], 1);
    }
}

// 3-phase exclusive scan over NBKT elements.
__global__ __launch_bounds__(1024) void k_scan1(const int* __restrict__ cnt2,
                                                int* __restrict__ boff2,
                                                int* __restrict__ bsum) {
    __shared__ int ws[16];
    int t = threadIdx.x, lane = t & 63, wv = t >> 6;
    int i = blockIdx.x * 1024 + t;
    int v = (i < NBKT) ? cnt2[i] : 0;
    int inc = v;
    for (int dd = 1; dd < 64; dd <<= 1) {
        int u = __shfl_up(inc, dd);
        if (lane >= dd) inc += u;
    }
    if (lane == 63) ws[wv] = inc;
    __syncthreads();
    if (t == 0) { int a = 0; for (int j = 0; j < 16; j++) { int x = ws[j]; ws[j] = a; a += x; } }
    __syncthreads();
    int ex = ws[wv] + inc - v;
    if (i < NBKT) boff2[i] = ex;
    if (t == 1023) bsum[blockIdx.x] = ex + v;
}

__global__ __launch_bounds__(1024) void k_scan2(int* __restrict__ bsum) {
    __shared__ int ws[16];
    int t = threadIdx.x, lane = t & 63, wv = t >> 6;
    int v = (t < NSB) ? bsum[t] : 0;
    int inc = v;
    for (int dd = 1; dd < 64; dd <<= 1) {
        int u = __shfl_up(inc, dd);
        if (lane >= dd) inc += u;
    }
    if (lane == 63) ws[wv] = inc;
    __syncthreads();
    if (t == 0) { int a = 0; for (int j = 0; j < 16; j++) { int x = ws[j]; ws[j] = a; a += x; } }
    __syncthreads();
    if (t < NSB) bsum[t] = ws[wv] + inc - v;
}

__global__ __launch_bounds__(1024) void k_scan3(int* __restrict__ boff2,
                                                const int* __restrict__ bsum,
                                                int* __restrict__ gcur2) {
    int i = blockIdx.x * 1024 + threadIdx.x;
    if (i < NBKT) {
        int f = boff2[i] + bsum[i >> 10];
        boff2[i] = f;
        gcur2[i] = f;
    }
    if (i == 0) boff2[NBKT] = NE;
}

// Counting-sort scatter: epack[pos] = src, grouped by (tile, rel, dl).
__global__ __launch_bounds__(1024) void k_scatter(
        const int* __restrict__ src, const int* __restrict__ dst,
        const int* __restrict__ et, int* __restrict__ gcur2,
        int* __restrict__ epack) {
    int i = blockIdx.x * 1024 + threadIdx.x;
    if (i < NE) {
        int d = dst[i];
        int key = (d >> 6) * 1280 + et[i] * 64 + (d & 63);
        int pos = atomicAdd(&gcur2[key], 1);
        epack[pos] = src[i];
    }
}

// h1b[n] = bf16(relu(bias0 + sum_r cnt[n,r]*W0[r]))   (layer 0, h = ones)
__global__ __launch_bounds__(128) void k_h1(const int* __restrict__ cnt2,
                                            const float* __restrict__ W0,
                                            const float* __restrict__ bias0,
                                            unsigned short* __restrict__ h1b) {
    int n = blockIdx.x, t = threadIdx.x;
    __shared__ float cs[NR];
    if (t < NR) cs[t] = (float)cnt2[(n >> 6) * 1280 + t * 64 + (n & 63)];
    __syncthreads();
    float acc = bias0[t];
    #pragma unroll
    for (int r = 0; r < NR; r++) acc += cs[r] * W0[r * D + t];
    h1b[n * D + t] = f2bf(fmaxf(acc, 0.f));
}

// Mega v3: one block per 64-dst tile, 8 waves, wave-specialized.
//  Producers (waves 4-7): per relation r+1, sum h1b rows per (dl) bucket in
//    f32 regs (4 thr/dl via col-quarters), cvt->bf16, ds_write to swizzled
//    S double-buffer; also prefetch W1b[r+1] to regs -> LDS single buffer.
//  Consumers (waves 0-3): 32 MFMA per relation from LDS S + LDS W,
//    acc[8] f32x4 persists across all 20 relations (no atomics anywhere).
//  Epilogue: relu(acc+bias1) -> LDS, then x@lin_w+lin_b -> out.
__global__ __launch_bounds__(512, 4) void k_mega(
        const int* __restrict__ epack, const int* __restrict__ boff2,
        const unsigned short* __restrict__ h1b,
        const unsigned short* __restrict__ W1b,
        const float* __restrict__ bias1, const float* __restrict__ lin_w,
        const float* __restrict__ lin_b, float* __restrict__ out) {
    __shared__ unsigned short Sb[2][8192];   // 2 x 64x128 bf16 (32 KB)
    __shared__ unsigned short Wl[16384];     // 128x128 bf16 fragment order (32 KB)
    __shared__ int epk[1792];                // tile's sorted src ids (7 KB)
    __shared__ int ooff[1284];               // tile's 1281 bucket offsets (5 KB)

    int t = threadIdx.x, tile = blockIdx.x;
    int wave = t >> 6, lane = t & 63;
    int kbase = tile * 1280;

    for (int i = t; i < 1281; i += 512) ooff[i] = boff2[kbase + i];
    __syncthreads();
    int tb = ooff[0];
    int nE = ooff[1280] - tb;
    for (int i = t; i < nE; i += 512) epk[i] = epack[tb + i];

    short8* Sb8_0 = (short8*)Sb[0];
    short8* Sb8_1 = (short8*)Sb[1];
    short8* Wl8   = (short8*)Wl;

    if (wave >= 4) {
        // ---------------- producers ----------------
        int pw = wave - 4;                  // col-quarter: cols pw*32..pw*32+31
        float s[32];
        short8 wreg[8];
        __syncthreads();                    // epk visible
        // prologue: r = 0
        {
            const short8* wg = (const short8*)W1b;
            #pragma unroll
            for (int j = 0; j < 8; j++) wreg[j] = wg[j * 256 + pw * 64 + lane];
            #pragma unroll
            for (int k = 0; k < 32; k++) s[k] = 0.f;
            int o0 = ooff[lane] - tb, o1 = ooff[lane + 1] - tb;
            for (int e = o0; e < o1; e++) {
                int sn = epk[e];
                const short8* hp = (const short8*)(h1b + sn * D) + pw * 4;
                #pragma unroll
                for (int j = 0; j < 4; j++) {
                    short8 v = hp[j];
                    #pragma unroll
                    for (int k = 0; k < 8; k++) s[j * 8 + k] += bf2f((unsigned short)v[k]);
                }
            }
            #pragma unroll
            for (int j = 0; j < 4; j++) {
                short8 o;
                #pragma unroll
                for (int k = 0; k < 8; k++) o[k] = (short)f2bf(s[j * 8 + k]);
                Sb8_0[lane * 16 + ((pw * 4 + j) ^ (lane & 15))] = o;
            }
            #pragma unroll
            for (int j = 0; j < 8; j++) Wl8[j * 256 + pw * 64 + lane] = wreg[j];
        }
        __syncthreads();                    // P1: S[0], Wl ready
        for (int r = 0; r < NR; r++) {
            if (r < NR - 1) {               // [A] prefetch r+1
                const short8* wg = (const short8*)W1b + (r + 1) * 2048;
                #pragma unroll
                for (int j = 0; j < 8; j++) wreg[j] = wg[j * 256 + pw * 64 + lane];
                #pragma unroll
                for (int k = 0; k < 32; k++) s[k] = 0.f;
                int idx = (r + 1) * 64 + lane;
                int o0 = ooff[idx] - tb, o1 = ooff[idx + 1] - tb;
                for (int e = o0; e < o1; e++) {
                    int sn = epk[e];
                    const short8* hp = (const short8*)(h1b + sn * D) + pw * 4;
                    #pragma unroll
                    for (int j = 0; j < 4; j++) {
                        short8 v = hp[j];
                        #pragma unroll
                        for (int k = 0; k < 8; k++) s[j * 8 + k] += bf2f((unsigned short)v[k]);
                    }
                }
            }
            __syncthreads();                // [B] consumers done with S[r&1], Wl
            if (r < NR - 1) {               // [C] publish r+1
                short8* Sdst = ((r + 1) & 1) ? Sb8_1 : Sb8_0;
                #pragma unroll
                for (int j = 0; j < 4; j++) {
                    short8 o;
                    #pragma unroll
                    for (int k = 0; k < 8; k++) o[k] = (short)f2bf(s[j * 8 + k]);
                    Sdst[lane * 16 + ((pw * 4 + j) ^ (lane & 15))] = o;
                }
                #pragma unroll
                for (int j = 0; j < 8; j++) Wl8[j * 256 + pw * 64 + lane] = wreg[j];
            }
            __syncthreads();                // [D] S[(r+1)&1], Wl ready
        }
    } else {
        // ---------------- consumers ----------------
        int wq = wave, row = lane & 15, gg = lane >> 4;
        int arow = wq * 16 + row;
        f32x4 acc[8];
        #pragma unroll
        for (int cb = 0; cb < 8; cb++) acc[cb] = (f32x4){0.f, 0.f, 0.f, 0.f};
        __syncthreads();                    // epk visible (pairs w/ producer)
        __syncthreads();                    // P1
        for (int r = 0; r < NR; r++) {
            const short8* Ssrc = (r & 1) ? Sb8_1 : Sb8_0;
            #pragma unroll
            for (int kc = 0; kc < 4; kc++) {
                short8 a = Ssrc[arow * 16 + (((kc * 4) + gg) ^ (arow & 15))];
                #pragma unroll
                for (int cb = 0; cb < 8; cb++) {
                    short8 b = Wl8[(kc * 8 + cb) * 64 + lane];
                    acc[cb] = __builtin_amdgcn_mfma_f32_16x16x32_bf16(a, b, acc[cb], 0, 0, 0);
                }
            }
            __syncthreads();                // [B]
            __syncthreads();                // [D]
        }
        // epilogue part 1: relu(acc + bias1) -> LDS (reuse Sb as f32[64][128])
        float* aggf = (float*)Sb;
        #pragma unroll
        for (int cb = 0; cb < 8; cb++) {
            int col = cb * 16 + row;
            float b1 = bias1[col];
            #pragma unroll
            for (int reg = 0; reg < 4; reg++) {
                int er = wq * 16 + gg * 4 + reg;
                aggf[er * D + col] = fmaxf(acc[cb][reg] + b1, 0.f);
            }
        }
    }
    __syncthreads();                        // aggf ready
    // epilogue part 2: linear 128 -> 64 (all 8 waves; lane = out col)
    float* aggf = (float*)Sb;
    for (int dl = wave; dl < 64; dl += 8) {
        int d = tile * 64 + dl;
        if (d < NN) {
            float a = lin_b[lane];
            #pragma unroll 8
            for (int k = 0; k < D; k++)
                a += aggf[dl * D + k] * lin_w[k * DO + lane];
            out[d * DO + lane] = a;
        }
    }
}

extern "C" void kernel_launch(void* const* d_in, const int* in_sizes, int n_in,
                              void* d_out, int out_size, void* d_ws, size_t ws_size,
                              hipStream_t stream) {
    const int*   src    = (const int*)d_in[0];
    const int*   dst    = (const int*)d_in[1];
    const int*   et     = (const int*)d_in[2];
    const float* basis0 = (const float*)d_in[4];
    const float* wcomp0 = (const float*)d_in[5];
    const float* bias0  = (const float*)d_in[6];
    const float* basis1 = (const float*)d_in[7];
    const float* wcomp1 = (const float*)d_in[8];
    const float* bias1  = (const float*)d_in[9];
    const float* lin_w  = (const float*)d_in[10];
    const float* lin_b  = (const float*)d_in[11];
    float* out = (float*)d_out;

    char* ws = (char*)d_ws;
    int*            cnt2  = (int*)           (ws + 0);
    int*            bsum  = (int*)           (ws + 4003840);
    int*            boff2 = (int*)           (ws + 4007808);
    int*            gcur2 = (int*)           (ws + 8011712);
    float*          W0    = (float*)         (ws + 12015616);
    unsigned short* W1b   = (unsigned short*)(ws + 12025856);
    unsigned short* h1b   = (unsigned short*)(ws + 12681216);
    int*            epack = (int*)           (ws + 25481216);

    hipMemsetAsync(ws, 0, 4003840, stream);   // zero cnt2

    k_weights<<<160, 256, 0, stream>>>(basis0, wcomp0, basis1, wcomp1, W0, W1b);
    k_hist<<<782, 1024, 0, stream>>>(dst, et, cnt2);
    k_scan1<<<NSB, 1024, 0, stream>>>(cnt2, boff2, bsum);
    k_scan2<<<1, 1024, 0, stream>>>(bsum);
    k_scan3<<<NSB, 1024, 0, stream>>>(boff2, bsum, gcur2);
    k_h1<<<NN, 128, 0, stream>>>(cnt2, W0, bias0, h1b);
    k_scatter<<<782, 1024, 0, stream>>>(src, dst, et, gcur2, epack);
    k_mega<<<NT, 512, 0, stream>>>(epack, boff2, h1b, W1b, bias1, lin_w, lin_b, out);
}

// Round 6
// 278.490 us; speedup vs baseline: 3.0993x; 1.0543x over previous
//
#include <hip/hip_runtime.h>
#include <hip/hip_bf16.h>

#define NN 50000      // nodes
#define NE 800000     // edges
#define NR 20         // relations
#define NB 8          // bases
#define D  128        // hidden dim
#define DO 64         // output dim
#define NT 782        // ceil(NN/64) dst tiles
#define NBKT (NT*1280) // (tile, rel, dl) buckets = 1,000,960
#define NSB 978       // ceil(NBKT/1024)

typedef __attribute__((ext_vector_type(8))) short short8;
typedef __attribute__((ext_vector_type(4))) float f32x4;

__device__ inline unsigned short f2bf(float f) {
    __hip_bfloat16 h = __float2bfloat16(f);
    return *reinterpret_cast<unsigned short*>(&h);
}
__device__ inline float bf2f(unsigned short u) {
    unsigned x = ((unsigned)u) << 16;
    float f;
    __builtin_memcpy(&f, &x, 4);
    return f;
}

// ---------------------------------------------------------------------------
// ws layout (bytes):
//   [0        ..  4,003,840) cnt2  NBKT int   -- zeroed each call; (tile,r,dl) hist
//   [4,003,840..  4,007,752) bsum  NSB int    -- scan block sums
//   [4,007,808..  8,011,652) boff2 NBKT+1 int -- bucket offsets
//   [8,011,712.. 12,015,552) gcur2 NBKT int   -- scatter cursors
//   [12,015,616..12,025,856) W0    NR*D f32
//   [12,025,856..12,681,216) W1b   NR*16384 bf16 (B-fragment order)
//   [12,681,216..25,481,216) h1b   NN*D bf16
//   [25,481,216..28,681,216) epack NE int (src ids, sorted by (tile,r,dl))
// ---------------------------------------------------------------------------

// W0[r,o] = sum_b wcomp0[r,b]*basis0[b,0,o]  (f32)
// W1b in MFMA B-fragment layout (r2/r3-verified):
//   task = ((rel*4 + kc)*8 + cb)*64 + lane ; elem e:
//   value = W1[rel][kc*32 + (lane>>4)*8 + e][cb*16 + (lane&15)]
__global__ __launch_bounds__(256) void k_weights(
        const float* __restrict__ basis0, const float* __restrict__ wcomp0,
        const float* __restrict__ basis1, const float* __restrict__ wcomp1,
        float* __restrict__ W0, unsigned short* __restrict__ W1b) {
    int idx = blockIdx.x * 256 + threadIdx.x;   // 0..40959
    if (idx < NR * D) {
        int r = idx / D, o = idx % D;
        float a = 0.f;
        #pragma unroll
        for (int b = 0; b < NB; b++) a += wcomp0[r * NB + b] * basis0[b * D + o];
        W0[idx] = a;
    }
    if (idx < NR * 4 * 8 * 64) {
        int lane = idx & 63;
        int cb   = (idx >> 6) & 7;
        int kc   = (idx >> 9) & 3;
        int rel  = idx >> 11;
        float wc[NB];
        #pragma unroll
        for (int b = 0; b < NB; b++) wc[b] = wcomp1[rel * NB + b];
        int o  = cb * 16 + (lane & 15);
        int i0 = kc * 32 + (lane >> 4) * 8;
        short8 v;
        #pragma unroll
        for (int e = 0; e < 8; e++) {
            int i = i0 + e;
            float a = 0.f;
            #pragma unroll
            for (int b = 0; b < NB; b++) a += wc[b] * basis1[(b * D + i) * D + o];
            v[e] = (short)f2bf(a);
        }
        *((short8*)W1b + idx) = v;
    }
}

// Histogram over (tile, rel, dl) buckets. Doubles as layer-0 (dst,rel) counts.
__global__ __launch_bounds__(1024) void k_hist(
        const int* __restrict__ dst, const int* __restrict__ et,
        int* __restrict__ cnt2) {
    int i = blockIdx.x * 1024 + threadIdx.x;
    if (i < NE) {
        int d = dst[i];
        int key = (d >> 6) * 1280 + et[i] * 64 + (d & 63);
        atomicAdd(&cnt2[key], 1);
    }
}

// 3-phase exclusive scan over NBKT elements.
__global__ __launch_bounds__(1024) void k_scan1(const int* __restrict__ cnt2,
                                                int* __restrict__ boff2,
                                                int* __restrict__ bsum) {
    __shared__ int ws[16];
    int t = threadIdx.x, lane = t & 63, wv = t >> 6;
    int i = blockIdx.x * 1024 + t;
    int v = (i < NBKT) ? cnt2[i] : 0;
    int inc = v;
    for (int dd = 1; dd < 64; dd <<= 1) {
        int u = __shfl_up(inc, dd);
        if (lane >= dd) inc += u;
    }
    if (lane == 63) ws[wv] = inc;
    __syncthreads();
    if (t == 0) { int a = 0; for (int j = 0; j < 16; j++) { int x = ws[j]; ws[j] = a; a += x; } }
    __syncthreads();
    int ex = ws[wv] + inc - v;
    if (i < NBKT) boff2[i] = ex;
    if (t == 1023) bsum[blockIdx.x] = ex + v;
}

__global__ __launch_bounds__(1024) void k_scan2(int* __restrict__ bsum) {
    __shared__ int ws[16];
    int t = threadIdx.x, lane = t & 63, wv = t >> 6;
    int v = (t < NSB) ? bsum[t] : 0;
    int inc = v;
    for (int dd = 1; dd < 64; dd <<= 1) {
        int u = __shfl_up(inc, dd);
        if (lane >= dd) inc += u;
    }
    if (lane == 63) ws[wv] = inc;
    __syncthreads();
    if (t == 0) { int a = 0; for (int j = 0; j < 16; j++) { int x = ws[j]; ws[j] = a; a += x; } }
    __syncthreads();
    if (t < NSB) bsum[t] = ws[wv] + inc - v;
}

__global__ __launch_bounds__(1024) void k_scan3(int* __restrict__ boff2,
                                                const int* __restrict__ bsum,
                                                int* __restrict__ gcur2) {
    int i = blockIdx.x * 1024 + threadIdx.x;
    if (i < NBKT) {
        int f = boff2[i] + bsum[i >> 10];
        boff2[i] = f;
        gcur2[i] = f;
    }
    if (i == 0) boff2[NBKT] = NE;
}

// Counting-sort scatter: epack[pos] = src, grouped by (tile, rel, dl).
__global__ __launch_bounds__(1024) void k_scatter(
        const int* __restrict__ src, const int* __restrict__ dst,
        const int* __restrict__ et, int* __restrict__ gcur2,
        int* __restrict__ epack) {
    int i = blockIdx.x * 1024 + threadIdx.x;
    if (i < NE) {
        int d = dst[i];
        int key = (d >> 6) * 1280 + et[i] * 64 + (d & 63);
        int pos = atomicAdd(&gcur2[key], 1);
        epack[pos] = src[i];
    }
}

// h1b: one block per 64-node tile. h1[n] = relu(bias0 + sum_r cnt[n,r]*W0[r]).
__global__ __launch_bounds__(512) void k_h1(const int* __restrict__ cnt2,
                                            const float* __restrict__ W0,
                                            const float* __restrict__ bias0,
                                            unsigned short* __restrict__ h1b) {
    __shared__ float cs[NR * 64];
    __shared__ float w0s[NR * D];
    int t = threadIdx.x, tile = blockIdx.x;
    for (int i = t; i < NR * 64; i += 512) cs[i] = (float)cnt2[tile * 1280 + i];
    for (int i = t; i < NR * D; i += 512) w0s[i] = W0[i];
    __syncthreads();
    int nl = t >> 3, cg = t & 7;
    int n = tile * 64 + nl;
    if (n < NN) {
        float a[16];
        #pragma unroll
        for (int j = 0; j < 16; j++) a[j] = bias0[cg * 16 + j];
        for (int r = 0; r < NR; r++) {
            float c = cs[r * 64 + nl];
            #pragma unroll
            for (int j = 0; j < 16; j++) a[j] += c * w0s[r * D + cg * 16 + j];
        }
        short8 o0, o1;
        #pragma unroll
        for (int j = 0; j < 8; j++) {
            o0[j] = (short)f2bf(fmaxf(a[j], 0.f));
            o1[j] = (short)f2bf(fmaxf(a[8 + j], 0.f));
        }
        *((short8*)(h1b + n * D + cg * 16))     = o0;
        *((short8*)(h1b + n * D + cg * 16 + 8)) = o1;
    }
}

// Mega v4: one block per 64-dst tile, 8 waves, NO wave specialization.
// Per relation r (all phases block-uniform; cnt from LDS ooff):
//   A: cooperatively stage <=64 raw h1b rows into LDS Raw (8 thr/row x 16B,
//      1024 parallel loads) + stage W1b[r] linearly into Wl.
//   B: thread (dl,cg) segment-sums its bucket's rows from LDS (f32 regs).
//   C: publish bf16 S-tile (XOR-swizzled for conflict-free A-frag reads).
//   D: 8 waves x 16 MFMA (4 rowblocks x 2 cb-halves); acc persists over r.
// Epilogue: relu(acc+bias1) -> LDS, then x@lin_w+lin_b -> out.
__global__ __launch_bounds__(512, 2) void k_mega(
        const int* __restrict__ epack, const int* __restrict__ boff2,
        const unsigned short* __restrict__ h1b,
        const unsigned short* __restrict__ W1b,
        const float* __restrict__ bias1, const float* __restrict__ lin_w,
        const float* __restrict__ lin_b, float* __restrict__ out) {
    __shared__ short Raw[64 * 136];          // 17,408 B (+16B/row pad: banks spread)
    __shared__ unsigned short Sl[64 * 128];  // 16,384 B swizzled A-tile
    __shared__ unsigned short Wl[16384];     // 32,768 B B-fragments (linear)
    __shared__ int ooff[1281];               //  5,124 B

    int t = threadIdx.x, tile = blockIdx.x;
    int wave = t >> 6, lane = t & 63;

    for (int i = t; i < 1281; i += 512) ooff[i] = boff2[tile * 1280 + i];
    __syncthreads();

    short8* Raw8 = (short8*)Raw;
    short8* Sl8  = (short8*)Sl;
    short8* Wl8  = (short8*)Wl;

    int le = t >> 3, lp = t & 7;             // load role: edge row, 16B part
    int dl = t >> 3, cg = t & 7;             // reduce role: dst-local, col-group
    int rb = wave & 3, ch = wave >> 2;       // mfma role: rowblock, cb-half
    int row = lane & 15, gg = lane >> 4;
    int arow = rb * 16 + row;

    f32x4 acc[4];
    #pragma unroll
    for (int j = 0; j < 4; j++) acc[j] = (f32x4){0.f, 0.f, 0.f, 0.f};

    for (int r = 0; r < NR; r++) {
        int rbase = ooff[r * 64];
        int cnt = ooff[r * 64 + 64] - rbase;     // block-uniform
        int nc = (cnt + 63) >> 6;
        float s[16];
        #pragma unroll
        for (int j = 0; j < 16; j++) s[j] = 0.f;

        if (cnt > 0) {
            // A: stage W (stride-512 linear copy, conflict-free) + Raw chunk 0
            const short8* wg = (const short8*)W1b + r * 2048;
            #pragma unroll
            for (int j = 0; j < 4; j++) Wl8[t + j * 512] = wg[t + j * 512];
            int m0 = min(64, cnt);
            if (le < m0) {
                int sn = epack[rbase + le];
                const short8* hp = (const short8*)(h1b + sn * D) + lp * 2;
                Raw8[le * 17 + lp * 2]     = hp[0];
                Raw8[le * 17 + lp * 2 + 1] = hp[1];
            }
        }
        __syncthreads();
        if (cnt > 0) {
            int o0 = ooff[r * 64 + dl] - rbase;
            int o1 = ooff[r * 64 + dl + 1] - rbase;
            // B: reduce chunk 0
            int hi = min(o1, min(64, cnt));
            for (int p = o0; p < hi; p++) {
                short8 v0 = Raw8[p * 17 + cg * 2];
                short8 v1 = Raw8[p * 17 + cg * 2 + 1];
                #pragma unroll
                for (int k = 0; k < 8; k++) {
                    s[k]     += bf2f((unsigned short)v0[k]);
                    s[8 + k] += bf2f((unsigned short)v1[k]);
                }
            }
            for (int c = 1; c < nc; c++) {
                __syncthreads();
                int cb0 = c * 64, m = min(64, cnt - cb0);
                if (le < m) {
                    int sn = epack[rbase + cb0 + le];
                    const short8* hp = (const short8*)(h1b + sn * D) + lp * 2;
                    Raw8[le * 17 + lp * 2]     = hp[0];
                    Raw8[le * 17 + lp * 2 + 1] = hp[1];
                }
                __syncthreads();
                int lo2 = max(o0 - cb0, 0), hi2 = min(o1 - cb0, m);
                for (int p = lo2; p < hi2; p++) {
                    short8 v0 = Raw8[p * 17 + cg * 2];
                    short8 v1 = Raw8[p * 17 + cg * 2 + 1];
                    #pragma unroll
                    for (int k = 0; k < 8; k++) {
                        s[k]     += bf2f((unsigned short)v0[k]);
                        s[8 + k] += bf2f((unsigned short)v1[k]);
                    }
                }
            }
            // C: publish swizzled bf16 S-tile
            short8 p0, p1;
            #pragma unroll
            for (int k = 0; k < 8; k++) {
                p0[k] = (short)f2bf(s[k]);
                p1[k] = (short)f2bf(s[8 + k]);
            }
            Sl8[dl * 16 + ((cg * 2)     ^ (dl & 15))] = p0;
            Sl8[dl * 16 + ((cg * 2 + 1) ^ (dl & 15))] = p1;
        }
        __syncthreads();
        if (cnt > 0) {
            // D: MFMA  (A from Sl, B from Wl)
            #pragma unroll
            for (int kc = 0; kc < 4; kc++) {
                short8 a = Sl8[arow * 16 + ((kc * 4 + gg) ^ (arow & 15))];
                #pragma unroll
                for (int j = 0; j < 4; j++) {
                    short8 b = Wl8[(kc * 8 + ch * 4 + j) * 64 + lane];
                    acc[j] = __builtin_amdgcn_mfma_f32_16x16x32_bf16(a, b, acc[j], 0, 0, 0);
                }
            }
        }
        __syncthreads();
    }

    // epilogue part 1: relu(acc + bias1) -> LDS f32 (reuse Wl space, 32 KB)
    float* aggf = (float*)Wl;
    #pragma unroll
    for (int j = 0; j < 4; j++) {
        int col = (ch * 4 + j) * 16 + row;
        float b1 = bias1[col];
        #pragma unroll
        for (int reg = 0; reg < 4; reg++) {
            int er = rb * 16 + gg * 4 + reg;
            aggf[er * D + col] = fmaxf(acc[j][reg] + b1, 0.f);
        }
    }
    __syncthreads();
    // epilogue part 2: linear 128 -> 64 (lane = out col; aggf reads broadcast)
    for (int dd = wave; dd < 64; dd += 8) {
        int d = tile * 64 + dd;
        if (d < NN) {
            float a = lin_b[lane];
            #pragma unroll 8
            for (int k = 0; k < D; k++)
                a += aggf[dd * D + k] * lin_w[k * DO + lane];
            out[d * DO + lane] = a;
        }
    }
}

extern "C" void kernel_launch(void* const* d_in, const int* in_sizes, int n_in,
                              void* d_out, int out_size, void* d_ws, size_t ws_size,
                              hipStream_t stream) {
    const int*   src    = (const int*)d_in[0];
    const int*   dst    = (const int*)d_in[1];
    const int*   et     = (const int*)d_in[2];
    const float* basis0 = (const float*)d_in[4];
    const float* wcomp0 = (const float*)d_in[5];
    const float* bias0  = (const float*)d_in[6];
    const float* basis1 = (const float*)d_in[7];
    const float* wcomp1 = (const float*)d_in[8];
    const float* bias1  = (const float*)d_in[9];
    const float* lin_w  = (const float*)d_in[10];
    const float* lin_b  = (const float*)d_in[11];
    float* out = (float*)d_out;

    char* ws = (char*)d_ws;
    int*            cnt2  = (int*)           (ws + 0);
    int*            bsum  = (int*)           (ws + 4003840);
    int*            boff2 = (int*)           (ws + 4007808);
    int*            gcur2 = (int*)           (ws + 8011712);
    float*          W0    = (float*)         (ws + 12015616);
    unsigned short* W1b   = (unsigned short*)(ws + 12025856);
    unsigned short* h1b   = (unsigned short*)(ws + 12681216);
    int*            epack = (int*)           (ws + 25481216);

    hipMemsetAsync(ws, 0, 4003840, stream);   // zero cnt2

    k_weights<<<160, 256, 0, stream>>>(basis0, wcomp0, basis1, wcomp1, W0, W1b);
    k_hist<<<782, 1024, 0, stream>>>(dst, et, cnt2);
    k_scan1<<<NSB, 1024, 0, stream>>>(cnt2, boff2, bsum);
    k_scan2<<<1, 1024, 0, stream>>>(bsum);
    k_scan3<<<NSB, 1024, 0, stream>>>(boff2, bsum, gcur2);
    k_h1<<<NT, 512, 0, stream>>>(cnt2, W0, bias0, h1b);
    k_scatter<<<782, 1024, 0, stream>>>(src, dst, et, gcur2, epack);
    k_mega<<<NT, 512, 0, stream>>>(epack, boff2, h1b, W1b, bias1, lin_w, lin_b, out);
}